// Round 4
// baseline (239.124 us; speedup 1.0000x reference)
//
#include <hip/hip_runtime.h>
#include <cstdint>

typedef unsigned short u16;
typedef __attribute__((ext_vector_type(8))) short bf16x8;   // 8 bf16 = 4 VGPRs
typedef __attribute__((ext_vector_type(4))) short bf16x4;   // 4 bf16 = 2 VGPRs
typedef __attribute__((ext_vector_type(4))) float f32x4;

#define S_LEN 2048
#define HDIM  1024
#define NHEAD 16

__device__ __forceinline__ float bf2f(u16 u){ return __uint_as_float(((uint32_t)u) << 16); }
__device__ __forceinline__ u16 f2bf(float f){
  uint32_t x = __float_as_uint(f);
  return (u16)((x + 0x7fffu + ((x >> 16) & 1u)) >> 16);   // RNE
}

// async global->LDS 16B (m97 idiom). LDS dest is wave-uniform base + lane*16.
__device__ __forceinline__ void gload_lds16(const void* g, void* l){
  __builtin_amdgcn_global_load_lds((const __attribute__((address_space(1))) void*)g,
                                   (__attribute__((address_space(3))) void*)l, 16, 0, 0);
}

// ---------------- f32 -> bf16 elementwise, batched over {q,k,v} via blockIdx.y ----------------
__global__ __launch_bounds__(256) void k_cvt3(const float* __restrict__ q, const float* __restrict__ k,
                                              const float* __restrict__ v, u16* __restrict__ oq,
                                              u16* __restrict__ ok, u16* __restrict__ ov){
  int z = blockIdx.y;
  const float* in = z == 0 ? q : (z == 1 ? k : v);
  u16* out = z == 0 ? oq : (z == 1 ? ok : ov);
  int i = blockIdx.x * 256 + threadIdx.x;     // 8 elems/thread, 4M elems total
  float4 f0 = *(const float4*)&in[(size_t)i * 8];
  float4 f1 = *(const float4*)&in[(size_t)i * 8 + 4];
  bf16x8 o;
  o[0] = (short)f2bf(f0.x); o[1] = (short)f2bf(f0.y);
  o[2] = (short)f2bf(f0.z); o[3] = (short)f2bf(f0.w);
  o[4] = (short)f2bf(f1.x); o[5] = (short)f2bf(f1.y);
  o[6] = (short)f2bf(f1.z); o[7] = (short)f2bf(f1.w);
  *(bf16x8*)&out[(size_t)i * 8] = o;
}

// ---------------- weight transpose + cvt, batched over 4 weights: wt[n][k] = w[k][n] ----------------
__global__ __launch_bounds__(256) void k_tr_w4(const float* __restrict__ w0, const float* __restrict__ w1,
                                               const float* __restrict__ w2, const float* __restrict__ w3,
                                               u16* __restrict__ o0, u16* __restrict__ o1,
                                               u16* __restrict__ o2, u16* __restrict__ o3){
  int z = blockIdx.z;
  const float* in = z == 0 ? w0 : (z == 1 ? w1 : (z == 2 ? w2 : w3));
  u16* out = z == 0 ? o0 : (z == 1 ? o1 : (z == 2 ? o2 : o3));
  __shared__ float t[64][65];
  int r0 = threadIdx.x >> 6;          // 0..3
  int c  = threadIdx.x & 63;
  int bx = blockIdx.x * 64, by = blockIdx.y * 64;
  #pragma unroll
  for (int i = 0; i < 64; i += 4) t[r0 + i][c] = in[(size_t)(by + r0 + i) * 1024 + bx + c];
  __syncthreads();
  #pragma unroll
  for (int i = 0; i < 64; i += 4) out[(size_t)(bx + r0 + i) * 1024 + by + c] = f2bf(t[c][r0 + i]);
}

// ---------------- v transpose (bf16->bf16): vt[b*16+h][d][s] = v[b][s][h*64+d] ----------------
__global__ __launch_bounds__(256) void k_tr_v(const u16* __restrict__ v, u16* __restrict__ vt){
  __shared__ u16 t[64][65];
  int r0 = threadIdx.x >> 6, c = threadIdx.x & 63;
  int s0 = blockIdx.x * 64;
  int bh = blockIdx.y;                // b*16+h
  int b = bh >> 4, h = bh & 15;
  const u16* src = v + (size_t)b * S_LEN * HDIM + h * 64;
  #pragma unroll
  for (int i = 0; i < 64; i += 4) t[r0 + i][c] = src[(size_t)(s0 + r0 + i) * HDIM + c];
  __syncthreads();
  u16* dst = vt + (size_t)bh * 64 * S_LEN + s0;
  #pragma unroll
  for (int i = 0; i < 64; i += 4) dst[(size_t)(r0 + i) * S_LEN + c] = t[c][r0 + i];
}

// ---------------- fused QKV GEMM: z in {0,1,2}; C[4096][1024] = A_z @ Wt_z^T, (acc+bias)*scale ----
__global__ __launch_bounds__(256) void k_gemm_qkv(const u16* __restrict__ A0, const u16* __restrict__ A1,
                                                  const u16* __restrict__ A2,
                                                  const u16* __restrict__ W0, const u16* __restrict__ W1,
                                                  const u16* __restrict__ W2,
                                                  const float* __restrict__ b0, const float* __restrict__ b1,
                                                  const float* __restrict__ b2,
                                                  u16* __restrict__ C0, u16* __restrict__ C1,
                                                  u16* __restrict__ C2)
{
  int z = blockIdx.z;
  const u16* A  = z == 0 ? A0 : (z == 1 ? A1 : A2);
  const u16* Wt = z == 0 ? W0 : (z == 1 ? W1 : W2);
  const float* bias = z == 0 ? b0 : (z == 1 ? b1 : b2);
  u16* C = z == 0 ? C0 : (z == 1 ? C1 : C2);
  float scale = z == 0 ? (1.0f / 64.0f) : 1.0f;   // fold 1/(8*8) into q

  __shared__ u16 As[128 * 32];       // unpadded: lane-linear for global_load_lds
  __shared__ u16 Bs[128 * 32];
  const int K = 1024, N = 1024;
  int tid = threadIdx.x;
  int lane = tid & 63, wave = tid >> 6;
  int quad = lane >> 4, c16 = lane & 15;
  int wm = wave >> 1, wn = wave & 1;
  int m0 = blockIdx.x * 128, n0 = blockIdx.y * 128;

  f32x4 acc[4][4] = {};

  for (int k0 = 0; k0 < K; k0 += 32) {
    #pragma unroll
    for (int i = 0; i < 2; i++) {
      int slot = tid + i * 256;                 // 128 rows x 4 chunks(16B)
      int r = slot >> 2, cc = (slot & 3) * 8;
      gload_lds16(&A [(size_t)(m0 + r) * K + k0 + cc], &As[slot * 8]);
      gload_lds16(&Wt[(size_t)(n0 + r) * K + k0 + cc], &Bs[slot * 8]);
    }
    __syncthreads();
    bf16x8 af[4], bfr[4];
    #pragma unroll
    for (int mt = 0; mt < 4; mt++) af[mt]  = *(const bf16x8*)&As[(wm * 64 + mt * 16 + c16) * 32 + quad * 8];
    #pragma unroll
    for (int nt = 0; nt < 4; nt++) bfr[nt] = *(const bf16x8*)&Bs[(wn * 64 + nt * 16 + c16) * 32 + quad * 8];
    #pragma unroll
    for (int mt = 0; mt < 4; mt++)
      #pragma unroll
      for (int nt = 0; nt < 4; nt++)
        acc[mt][nt] = __builtin_amdgcn_mfma_f32_16x16x32_bf16(af[mt], bfr[nt], acc[mt][nt], 0, 0, 0);
    __syncthreads();
  }

  #pragma unroll
  for (int nt = 0; nt < 4; nt++) {
    int gc = n0 + wn * 64 + nt * 16 + c16;
    float bv = bias[gc];
    #pragma unroll
    for (int mt = 0; mt < 4; mt++)
      #pragma unroll
      for (int r = 0; r < 4; r++) {
        int gr = m0 + wm * 64 + mt * 16 + quad * 4 + r;
        C[(size_t)gr * N + gc] = f2bf((acc[mt][nt][r] + bv) * scale);
      }
  }
}

// ---------------- O-proj GEMM: 128x64 tiles (512 blocks, 2/CU), f32 out ----------------
__global__ __launch_bounds__(256) void k_gemm_o(const u16* __restrict__ A, const u16* __restrict__ Wt,
                                                const float* __restrict__ bias, float* __restrict__ C)
{
  __shared__ u16 As[128 * 32];
  __shared__ u16 Bs[64 * 32];
  const int K = 1024, N = 1024;
  int tid = threadIdx.x;
  int lane = tid & 63, wave = tid >> 6;
  int quad = lane >> 4, c16 = lane & 15;
  int wm = wave >> 1, wn = wave & 1;            // wave tile 64x32
  int m0 = blockIdx.x * 128, n0 = blockIdx.y * 64;

  f32x4 acc[4][2] = {};

  for (int k0 = 0; k0 < K; k0 += 32) {
    #pragma unroll
    for (int i = 0; i < 2; i++) {                // A: 128 rows x 4 chunks = 512 chunks
      int slot = tid + i * 256;
      int r = slot >> 2, cc = (slot & 3) * 8;
      gload_lds16(&A[(size_t)(m0 + r) * K + k0 + cc], &As[slot * 8]);
    }
    {                                            // B: 64 rows x 4 chunks = 256 chunks
      int r = tid >> 2, cc = (tid & 3) * 8;
      gload_lds16(&Wt[(size_t)(n0 + r) * K + k0 + cc], &Bs[tid * 8]);
    }
    __syncthreads();
    bf16x8 af[4], bfr[2];
    #pragma unroll
    for (int mt = 0; mt < 4; mt++) af[mt]  = *(const bf16x8*)&As[(wm * 64 + mt * 16 + c16) * 32 + quad * 8];
    #pragma unroll
    for (int nt = 0; nt < 2; nt++) bfr[nt] = *(const bf16x8*)&Bs[(wn * 32 + nt * 16 + c16) * 32 + quad * 8];
    #pragma unroll
    for (int mt = 0; mt < 4; mt++)
      #pragma unroll
      for (int nt = 0; nt < 2; nt++)
        acc[mt][nt] = __builtin_amdgcn_mfma_f32_16x16x32_bf16(af[mt], bfr[nt], acc[mt][nt], 0, 0, 0);
    __syncthreads();
  }

  #pragma unroll
  for (int nt = 0; nt < 2; nt++) {
    int gc = n0 + wn * 32 + nt * 16 + c16;
    float bv = bias[gc];
    #pragma unroll
    for (int mt = 0; mt < 4; mt++)
      #pragma unroll
      for (int r = 0; r < 4; r++) {
        int gr = m0 + wm * 64 + mt * 16 + quad * 4 + r;
        C[(size_t)gr * N + gc] = acc[mt][nt][r] + bv;
      }
  }
}

// ---------------- flash attention: 64 q-rows/block, 4 waves x 16 q-rows, double-buffered staging.
// Verified r1 sync structure (prefetch at top of iter, one __syncthreads per tile).
// SWAPPED QK^T (S^T = mfma(K,Q)): lane(c16,quad) holds S[kv=kvt*16+quad*4+r][q=c16] = the
// 16x16x16 MFMA A-fragment layout for PV. Softmax fully in-register.
// This round: occupancy 2 -> 4 blocks/CU (grid x2 via 64-q blocks; Msall LDS dropped — mask
// terms computed per tile from the L2-resident global mask). LDS 36864 B, launch_bounds(256,4).
__global__ __launch_bounds__(256, 4) void k_attn(const u16* __restrict__ Qm,
                                                 const u16* __restrict__ Km,
                                                 const u16* __restrict__ VTm,
                                                 const float* __restrict__ mask,
                                                 u16* __restrict__ Om)
{
  __shared__ u16 KV[2][9216];        // [buf][K: 64x72 | VT: 64x72] (72 = 9 chunks of 16B)
  const int NT = S_LEN / 64;
  int tid = threadIdx.x;
  int lane = tid & 63, wave = tid >> 6;         // wave 0..3
  int quad = lane >> 4, c16 = lane & 15;
  int qb = blockIdx.x, h = blockIdx.y, b = blockIdx.z;
  const size_t SH = (size_t)S_LEN * HDIM;
  const u16* Qbase  = Qm + (size_t)b * SH + (size_t)qb * 64 * HDIM + h * 64;
  const u16* Kbase  = Km + (size_t)b * SH + h * 64;
  const u16* VTbase = VTm + (size_t)(b * NHEAD + h) * 64 * S_LEN;
  const float* Mbase = mask + (size_t)b * S_LEN;

  // async stage K(64x64)+VT(64x64) for tile at s0 into buffer bb (1152 chunks over 5x256,
  // branch boundaries on wave edges; chunk 8 of each 9-chunk row is pad -> dummy load)
  auto stage = [&](int s0, int bb) {
    #pragma unroll
    for (int i = 0; i < 5; i++) {
      int c = i * 256 + tid;
      if (c < 576) {
        int r = c / 9, cc = c - r * 9;
        int col = (cc == 8) ? 0 : cc * 8;
        gload_lds16(&Kbase[(size_t)(s0 + r) * HDIM + col], &KV[bb][c * 8]);
      } else if (c < 1152) {
        int c2 = c - 576;
        int r = c2 / 9, cc = c2 - r * 9;
        int col = (cc == 8) ? 0 : cc * 8;
        gload_lds16(&VTbase[(size_t)r * S_LEN + s0 + col], &KV[bb][4608 + c2 * 8]);
      }
    }
  };

  int qw0 = wave * 16;                          // wave owns 16 q-rows of the 64

  // Q fragments in registers (loop-invariant, B-side of the swapped QK^T)
  bf16x8 bq[2];
  #pragma unroll
  for (int kk = 0; kk < 2; kk++)
    bq[kk] = *(const bf16x8*)&Qbase[(size_t)(qw0 + c16) * HDIM + kk * 32 + quad * 8];

  f32x4 oacc[4] = {};          // D[q=quad*4+r][d=dt*16+c16]
  float lsq = 0.0f;            // per-lane partial denominator for q = c16

  stage(0, 0);
  __syncthreads();                              // tile 0 ready

  for (int kt = 0; kt < NT; kt++) {
    int s0 = kt * 64;
    int cb = kt & 1;
    const u16* Kb = &KV[cb][0];
    const u16* Vb = &KV[cb][4608];
    if (kt + 1 < NT) stage(s0 + 64, cb ^ 1);    // async prefetch, drained by end barrier

    // mask additive terms from global (L2-resident, uniform across the 16 c16-lanes)
    f32x4 madd[4];
    #pragma unroll
    for (int kvt = 0; kvt < 4; kvt++) {
      f32x4 m = *(const f32x4*)&Mbase[s0 + kvt * 16 + quad * 4];
      #pragma unroll
      for (int r = 0; r < 4; r++) madd[kvt][r] = (1.0f - m[r]) * (-1.25e9f);   // (-1e10)/8
    }

    // S^T = K Q^T; mask folded into the k-slice-0 MFMA's C operand
    bf16x8 ak0[4], ak1[4];
    #pragma unroll
    for (int kvt = 0; kvt < 4; kvt++) {
      ak0[kvt] = *(const bf16x8*)&Kb[(kvt * 16 + c16) * 72 + quad * 8];
      ak1[kvt] = *(const bf16x8*)&Kb[(kvt * 16 + c16) * 72 + 32 + quad * 8];
    }
    f32x4 sacc[4];
    __builtin_amdgcn_s_setprio(1);
    #pragma unroll
    for (int kvt = 0; kvt < 4; kvt++)
      sacc[kvt] = __builtin_amdgcn_mfma_f32_16x16x32_bf16(ak0[kvt], bq[0], madd[kvt], 0, 0, 0);
    #pragma unroll
    for (int kvt = 0; kvt < 4; kvt++)
      sacc[kvt] = __builtin_amdgcn_mfma_f32_16x16x32_bf16(ak1[kvt], bq[1], sacc[kvt], 0, 0, 0);
    __builtin_amdgcn_s_setprio(0);

    // P = exp(S + maskterm) fully in-register; pack to 16x16x16 A-fragments via v_cvt_pk_bf16_f32
    bf16x4 pa[4];
    #pragma unroll
    for (int kvt = 0; kvt < 4; kvt++) {
      float p0 = __expf(sacc[kvt][0]);
      float p1 = __expf(sacc[kvt][1]);
      float p2 = __expf(sacc[kvt][2]);
      float p3 = __expf(sacc[kvt][3]);
      lsq += (p0 + p1) + (p2 + p3);
      union { uint32_t u[2]; bf16x4 v; } cv;
      asm("v_cvt_pk_bf16_f32 %0, %1, %2" : "=v"(cv.u[0]) : "v"(p0), "v"(p1));
      asm("v_cvt_pk_bf16_f32 %0, %1, %2" : "=v"(cv.u[1]) : "v"(p2), "v"(p3));
      pa[kvt] = cv.v;
    }

    // O += P V : 16x16x16 MFMAs, K=16 slice = kvt; B rows = d from VT half of LDS
    __builtin_amdgcn_s_setprio(1);
    #pragma unroll
    for (int kvt = 0; kvt < 4; kvt++) {
      bf16x4 vb[4];
      #pragma unroll
      for (int dt = 0; dt < 4; dt++)
        vb[dt] = *(const bf16x4*)&Vb[(dt * 16 + c16) * 72 + kvt * 16 + quad * 4];
      #pragma unroll
      for (int dt = 0; dt < 4; dt++)
        oacc[dt] = __builtin_amdgcn_mfma_f32_16x16x16bf16_1k(pa[kvt], vb[dt], oacc[dt], 0, 0, 0);
    }
    __builtin_amdgcn_s_setprio(0);
    __syncthreads();      // (a) all reads of buf cb done -> reusable; (b) vmcnt(0) drains prefetch
  }

  // denominator: reduce per-lane partials across the 4 quads (each c16 group holds one q-row)
  {
    float v = lsq;
    v += __shfl_xor(v, 16);
    v += __shfl_xor(v, 32);
    lsq = v;
  }

  u16* Obase = Om + (size_t)b * SH + (size_t)qb * 64 * HDIM + h * 64;
  #pragma unroll
  for (int r = 0; r < 4; r++) {
    float l = __shfl(lsq, quad * 4 + r);     // denominator for q-row quad*4+r (lane idx 0..15)
    float rinv = 1.0f / l;
    int lr = qw0 + quad * 4 + r;
    #pragma unroll
    for (int dt = 0; dt < 4; dt++)
      Obase[(size_t)lr * HDIM + dt * 16 + c16] = f2bf(oacc[dt][r] * rinv);
  }
}

extern "C" void kernel_launch(void* const* d_in, const int* in_sizes, int n_in,
                              void* d_out, int out_size, void* d_ws, size_t ws_size,
                              hipStream_t stream)
{
  (void)in_sizes; (void)n_in; (void)out_size; (void)ws_size;
  const float* q_in = (const float*)d_in[0];
  const float* k_in = (const float*)d_in[1];
  const float* v_in = (const float*)d_in[2];
  const float* mask = (const float*)d_in[3];
  const float* wq   = (const float*)d_in[4];
  const float* bq   = (const float*)d_in[5];
  const float* wk   = (const float*)d_in[6];
  const float* bk   = (const float*)d_in[7];
  const float* wv   = (const float*)d_in[8];
  const float* bv   = (const float*)d_in[9];
  const float* wo   = (const float*)d_in[10];
  const float* bo   = (const float*)d_in[11];

  u16* ws  = (u16*)d_ws;                 // bf16 elems: 4x1M wt + 3x4M in + 5x4M acts = 72 MB
  u16* wqt = ws;
  u16* wkt = wqt + (1u << 20);
  u16* wvt = wkt + (1u << 20);
  u16* wot = wvt + (1u << 20);
  u16* qi_ = wot + (1u << 20);
  u16* ki_ = qi_ + (4u << 20);
  u16* vi_ = ki_ + (4u << 20);
  u16* qb_ = vi_ + (4u << 20);
  u16* kb_ = qb_ + (4u << 20);
  u16* vb_ = kb_ + (4u << 20);
  u16* vtb = vb_ + (4u << 20);
  u16* ob_ = vtb + (4u << 20);

  dim3 blk(256);
  k_cvt3<<<dim3(2048, 3), blk, 0, stream>>>(q_in, k_in, v_in, qi_, ki_, vi_);
  k_tr_w4<<<dim3(16, 16, 4), blk, 0, stream>>>(wq, wk, wv, wo, wqt, wkt, wvt, wot);
  k_gemm_qkv<<<dim3(32, 8, 3), blk, 0, stream>>>(qi_, ki_, vi_, wqt, wkt, wvt, bq, bk, bv, qb_, kb_, vb_);
  k_tr_v<<<dim3(32, 32), blk, 0, stream>>>(vb_, vtb);
  k_attn<<<dim3(32, 16, 2), blk, 0, stream>>>(qb_, kb_, vtb, mask, ob_);
  k_gemm_o<<<dim3(32, 16), blk, 0, stream>>>(ob_, wot, bo, (float*)d_out);
}

// Round 6
// 226.146 us; speedup vs baseline: 1.0574x; 1.0574x over previous
//
#include <hip/hip_runtime.h>
#include <cstdint>

typedef unsigned short u16;
typedef __attribute__((ext_vector_type(8))) short bf16x8;   // 8 bf16 = 4 VGPRs
typedef __attribute__((ext_vector_type(4))) short bf16x4;   // 4 bf16 = 2 VGPRs
typedef __attribute__((ext_vector_type(4))) float f32x4;

#define S_LEN 2048
#define HDIM  1024
#define NHEAD 16

__device__ __forceinline__ float bf2f(u16 u){ return __uint_as_float(((uint32_t)u) << 16); }
__device__ __forceinline__ u16 f2bf(float f){
  uint32_t x = __float_as_uint(f);
  return (u16)((x + 0x7fffu + ((x >> 16) & 1u)) >> 16);   // RNE
}

// 2^x via the native v_exp_f32 (gfx950: v_exp_f32 computes 2^S0)
__device__ __forceinline__ float exp2_fast(float x){
  float r; asm("v_exp_f32 %0, %1" : "=v"(r) : "v"(x)); return r;
}

// async global->LDS 16B (m97 idiom). LDS dest is wave-uniform base + lane*16.
__device__ __forceinline__ void gload_lds16(const void* g, void* l){
  __builtin_amdgcn_global_load_lds((const __attribute__((address_space(1))) void*)g,
                                   (__attribute__((address_space(3))) void*)l, 16, 0, 0);
}

// ---------------- f32 -> bf16 elementwise, batched over {q,k,v} via blockIdx.y ----------------
__global__ __launch_bounds__(256) void k_cvt3(const float* __restrict__ q, const float* __restrict__ k,
                                              const float* __restrict__ v, u16* __restrict__ oq,
                                              u16* __restrict__ ok, u16* __restrict__ ov){
  int z = blockIdx.y;
  const float* in = z == 0 ? q : (z == 1 ? k : v);
  u16* out = z == 0 ? oq : (z == 1 ? ok : ov);
  int i = blockIdx.x * 256 + threadIdx.x;     // 8 elems/thread, 4M elems total
  float4 f0 = *(const float4*)&in[(size_t)i * 8];
  float4 f1 = *(const float4*)&in[(size_t)i * 8 + 4];
  bf16x8 o;
  o[0] = (short)f2bf(f0.x); o[1] = (short)f2bf(f0.y);
  o[2] = (short)f2bf(f0.z); o[3] = (short)f2bf(f0.w);
  o[4] = (short)f2bf(f1.x); o[5] = (short)f2bf(f1.y);
  o[6] = (short)f2bf(f1.z); o[7] = (short)f2bf(f1.w);
  *(bf16x8*)&out[(size_t)i * 8] = o;
}

// ---------------- weight transpose + cvt, batched over 4 weights: wt[n][k] = w[k][n] ----------------
__global__ __launch_bounds__(256) void k_tr_w4(const float* __restrict__ w0, const float* __restrict__ w1,
                                               const float* __restrict__ w2, const float* __restrict__ w3,
                                               u16* __restrict__ o0, u16* __restrict__ o1,
                                               u16* __restrict__ o2, u16* __restrict__ o3){
  int z = blockIdx.z;
  const float* in = z == 0 ? w0 : (z == 1 ? w1 : (z == 2 ? w2 : w3));
  u16* out = z == 0 ? o0 : (z == 1 ? o1 : (z == 2 ? o2 : o3));
  __shared__ float t[64][65];
  int r0 = threadIdx.x >> 6;          // 0..3
  int c  = threadIdx.x & 63;
  int bx = blockIdx.x * 64, by = blockIdx.y * 64;
  #pragma unroll
  for (int i = 0; i < 64; i += 4) t[r0 + i][c] = in[(size_t)(by + r0 + i) * 1024 + bx + c];
  __syncthreads();
  #pragma unroll
  for (int i = 0; i < 64; i += 4) out[(size_t)(bx + r0 + i) * 1024 + by + c] = f2bf(t[c][r0 + i]);
}

// ---------------- v transpose (bf16->bf16): vt[b*16+h][d][s] = v[b][s][h*64+d] ----------------
__global__ __launch_bounds__(256) void k_tr_v(const u16* __restrict__ v, u16* __restrict__ vt){
  __shared__ u16 t[64][65];
  int r0 = threadIdx.x >> 6, c = threadIdx.x & 63;
  int s0 = blockIdx.x * 64;
  int bh = blockIdx.y;                // b*16+h
  int b = bh >> 4, h = bh & 15;
  const u16* src = v + (size_t)b * S_LEN * HDIM + h * 64;
  #pragma unroll
  for (int i = 0; i < 64; i += 4) t[r0 + i][c] = src[(size_t)(s0 + r0 + i) * HDIM + c];
  __syncthreads();
  u16* dst = vt + (size_t)bh * 64 * S_LEN + s0;
  #pragma unroll
  for (int i = 0; i < 64; i += 4) dst[(size_t)(r0 + i) * S_LEN + c] = t[c][r0 + i];
}

// ---------------- fused QKV GEMM: z in {0,1,2}; C[4096][1024] = A_z @ Wt_z^T, (acc+bias)*scale ----
// q is additionally scaled by log2(e) so attention softmax can use exp2 (v_exp_f32 native).
__global__ __launch_bounds__(256) void k_gemm_qkv(const u16* __restrict__ A0, const u16* __restrict__ A1,
                                                  const u16* __restrict__ A2,
                                                  const u16* __restrict__ W0, const u16* __restrict__ W1,
                                                  const u16* __restrict__ W2,
                                                  const float* __restrict__ b0, const float* __restrict__ b1,
                                                  const float* __restrict__ b2,
                                                  u16* __restrict__ C0, u16* __restrict__ C1,
                                                  u16* __restrict__ C2)
{
  int z = blockIdx.z;
  const u16* A  = z == 0 ? A0 : (z == 1 ? A1 : A2);
  const u16* Wt = z == 0 ? W0 : (z == 1 ? W1 : W2);
  const float* bias = z == 0 ? b0 : (z == 1 ? b1 : b2);
  u16* C = z == 0 ? C0 : (z == 1 ? C1 : C2);
  float scale = z == 0 ? (1.44269504f / 64.0f) : 1.0f;   // fold 1/(8*8) and log2e into q

  __shared__ u16 As[128 * 32];       // unpadded: lane-linear for global_load_lds
  __shared__ u16 Bs[128 * 32];
  const int K = 1024, N = 1024;
  int tid = threadIdx.x;
  int lane = tid & 63, wave = tid >> 6;
  int quad = lane >> 4, c16 = lane & 15;
  int wm = wave >> 1, wn = wave & 1;
  int m0 = blockIdx.x * 128, n0 = blockIdx.y * 128;

  f32x4 acc[4][4] = {};

  for (int k0 = 0; k0 < K; k0 += 32) {
    #pragma unroll
    for (int i = 0; i < 2; i++) {
      int slot = tid + i * 256;                 // 128 rows x 4 chunks(16B)
      int r = slot >> 2, cc = (slot & 3) * 8;
      gload_lds16(&A [(size_t)(m0 + r) * K + k0 + cc], &As[slot * 8]);
      gload_lds16(&Wt[(size_t)(n0 + r) * K + k0 + cc], &Bs[slot * 8]);
    }
    __syncthreads();
    bf16x8 af[4], bfr[4];
    #pragma unroll
    for (int mt = 0; mt < 4; mt++) af[mt]  = *(const bf16x8*)&As[(wm * 64 + mt * 16 + c16) * 32 + quad * 8];
    #pragma unroll
    for (int nt = 0; nt < 4; nt++) bfr[nt] = *(const bf16x8*)&Bs[(wn * 64 + nt * 16 + c16) * 32 + quad * 8];
    #pragma unroll
    for (int mt = 0; mt < 4; mt++)
      #pragma unroll
      for (int nt = 0; nt < 4; nt++)
        acc[mt][nt] = __builtin_amdgcn_mfma_f32_16x16x32_bf16(af[mt], bfr[nt], acc[mt][nt], 0, 0, 0);
    __syncthreads();
  }

  #pragma unroll
  for (int nt = 0; nt < 4; nt++) {
    int gc = n0 + wn * 64 + nt * 16 + c16;
    float bv = bias[gc];
    #pragma unroll
    for (int mt = 0; mt < 4; mt++)
      #pragma unroll
      for (int r = 0; r < 4; r++) {
        int gr = m0 + wm * 64 + mt * 16 + quad * 4 + r;
        C[(size_t)gr * N + gc] = f2bf((acc[mt][nt][r] + bv) * scale);
      }
  }
}

// ---------------- O-proj GEMM: 128x64 tiles (512 blocks, 2/CU), f32 out ----------------
__global__ __launch_bounds__(256) void k_gemm_o(const u16* __restrict__ A, const u16* __restrict__ Wt,
                                                const float* __restrict__ bias, float* __restrict__ C)
{
  __shared__ u16 As[128 * 32];
  __shared__ u16 Bs[64 * 32];
  const int K = 1024, N = 1024;
  int tid = threadIdx.x;
  int lane = tid & 63, wave = tid >> 6;
  int quad = lane >> 4, c16 = lane & 15;
  int wm = wave >> 1, wn = wave & 1;            // wave tile 64x32
  int m0 = blockIdx.x * 128, n0 = blockIdx.y * 64;

  f32x4 acc[4][2] = {};

  for (int k0 = 0; k0 < K; k0 += 32) {
    #pragma unroll
    for (int i = 0; i < 2; i++) {                // A: 128 rows x 4 chunks = 512 chunks
      int slot = tid + i * 256;
      int r = slot >> 2, cc = (slot & 3) * 8;
      gload_lds16(&A[(size_t)(m0 + r) * K + k0 + cc], &As[slot * 8]);
    }
    {                                            // B: 64 rows x 4 chunks = 256 chunks
      int r = tid >> 2, cc = (tid & 3) * 8;
      gload_lds16(&Wt[(size_t)(n0 + r) * K + k0 + cc], &Bs[tid * 8]);
    }
    __syncthreads();
    bf16x8 af[4], bfr[2];
    #pragma unroll
    for (int mt = 0; mt < 4; mt++) af[mt]  = *(const bf16x8*)&As[(wm * 64 + mt * 16 + c16) * 32 + quad * 8];
    #pragma unroll
    for (int nt = 0; nt < 2; nt++) bfr[nt] = *(const bf16x8*)&Bs[(wn * 32 + nt * 16 + c16) * 32 + quad * 8];
    #pragma unroll
    for (int mt = 0; mt < 4; mt++)
      #pragma unroll
      for (int nt = 0; nt < 2; nt++)
        acc[mt][nt] = __builtin_amdgcn_mfma_f32_16x16x32_bf16(af[mt], bfr[nt], acc[mt][nt], 0, 0, 0);
    __syncthreads();
  }

  #pragma unroll
  for (int nt = 0; nt < 2; nt++) {
    int gc = n0 + wn * 32 + nt * 16 + c16;
    float bv = bias[gc];
    #pragma unroll
    for (int mt = 0; mt < 4; mt++)
      #pragma unroll
      for (int r = 0; r < 4; r++) {
        int gr = m0 + wm * 64 + mt * 16 + quad * 4 + r;
        C[(size_t)gr * N + gc] = acc[mt][nt][r] + bv;
      }
  }
}

// ---------------- flash attention: 128 q-rows/block, r1 sync skeleton (verified), but wave
// decomposition = 2 q-halves x 2 kv-halves: wave (wq,wkv) computes q[wq*64..+64) x kv[wkv*32..+32)
// of each 64-kv tile. K-side LDS reads 8->4 b128, V-side 16->8 b64 per wave per tile (traffic /2);
// MFMA/exp totals work-conserved. kv-split partial sums (oacc, lsq) are combined once at the end
// through the then-dead KV LDS buffer (plain __syncthreads, no new in-loop sync).
// SWAPPED QK^T (S^T = mfma(K,Q)): lane(c16,quad) holds S[kv][q=qt*16+c16] = 16x16x16 A-frag for PV.
// Softmax fully in-register; exp2 path (log2e pre-folded into q and mask terms).
__global__ __launch_bounds__(256, 2) void k_attn(const u16* __restrict__ Qm,
                                                 const u16* __restrict__ Km,
                                                 const u16* __restrict__ VTm,
                                                 const float* __restrict__ mask,
                                                 u16* __restrict__ Om)
{
  __shared__ u16 KV[2][9216];        // [buf][K: 64x72 | VT: 64x72] (72 = 9 chunks of 16B)
  __shared__ float Msall[S_LEN];     // mask additive terms (pre-scaled by log2e), staged once
  const int NT = S_LEN / 64;
  int tid = threadIdx.x;
  int lane = tid & 63, wave = tid >> 6;         // wave 0..3
  int quad = lane >> 4, c16 = lane & 15;
  int wq = wave >> 1, wkv = wave & 1;           // q-half, kv-half
  int qb = blockIdx.x, h = blockIdx.y, b = blockIdx.z;
  const size_t SH = (size_t)S_LEN * HDIM;
  const u16* Qbase  = Qm + (size_t)b * SH + (size_t)qb * 128 * HDIM + h * 64;
  const u16* Kbase  = Km + (size_t)b * SH + h * 64;
  const u16* VTbase = VTm + (size_t)(b * NHEAD + h) * 64 * S_LEN;
  const float* Mbase = mask + (size_t)b * S_LEN;

  // async stage K(64x64)+VT(64x64) for tile at s0 into buffer bb (1152 chunks over 5x256,
  // branch boundaries on wave edges; chunk 8 of each 9-chunk row is pad -> dummy load)
  auto stage = [&](int s0, int bb) {
    #pragma unroll
    for (int i = 0; i < 5; i++) {
      int c = i * 256 + tid;
      if (c < 576) {
        int r = c / 9, cc = c - r * 9;
        int col = (cc == 8) ? 0 : cc * 8;
        gload_lds16(&Kbase[(size_t)(s0 + r) * HDIM + col], &KV[bb][c * 8]);
      } else if (c < 1152) {
        int c2 = c - 576;
        int r = c2 / 9, cc = c2 - r * 9;
        int col = (cc == 8) ? 0 : cc * 8;
        gload_lds16(&VTbase[(size_t)r * S_LEN + s0 + col], &KV[bb][4608 + c2 * 8]);
      }
    }
  };

  stage(0, 0);
  for (int i = tid; i < S_LEN; i += 256) Msall[i] = (1.0f - Mbase[i]) * (-1.8033688e9f);  // (-1e10)/8*log2e

  int qw0 = wq * 64;                            // wave's 64 q-rows
  int kv0 = wkv * 32;                           // wave's 32-kv slice within each tile

  // Q fragments in registers (loop-invariant, B-side of the swapped QK^T)
  bf16x8 bq[4][2];
  #pragma unroll
  for (int qt = 0; qt < 4; qt++)
    #pragma unroll
    for (int kk = 0; kk < 2; kk++)
      bq[qt][kk] = *(const bf16x8*)&Qbase[(size_t)(qw0 + qt * 16 + c16) * HDIM + kk * 32 + quad * 8];

  f32x4 oacc[4][4] = {};       // D[q=qt*16+quad*4+r][d=dt*16+c16], partial over this wave's kv slices
  float lsq[4] = {};           // per-lane partial denominators for q = qt*16+c16

  __syncthreads();                              // tile 0 + Msall ready

  for (int kt = 0; kt < NT; kt++) {
    int s0 = kt * 64;
    int cb = kt & 1;
    const u16* Kb = &KV[cb][0];
    const u16* Vb = &KV[cb][4608];
    if (kt + 1 < NT) stage(s0 + 64, cb ^ 1);    // async prefetch, drained by end barrier

    // mask terms for this wave's kv slice (uniform across c16 -> LDS broadcast)
    f32x4 madd[2];
    #pragma unroll
    for (int kv2 = 0; kv2 < 2; kv2++) madd[kv2] = *(const f32x4*)&Msall[s0 + kv0 + kv2 * 16 + quad * 4];

    // S^T = K Q^T over the 32-kv slice; mask folded into the k-slice-0 MFMA's C operand
    bf16x8 ak0[2], ak1[2];
    #pragma unroll
    for (int kv2 = 0; kv2 < 2; kv2++) {
      ak0[kv2] = *(const bf16x8*)&Kb[(kv0 + kv2 * 16 + c16) * 72 + quad * 8];
      ak1[kv2] = *(const bf16x8*)&Kb[(kv0 + kv2 * 16 + c16) * 72 + 32 + quad * 8];
    }
    f32x4 sacc[2][4];
    __builtin_amdgcn_s_setprio(1);
    #pragma unroll
    for (int kv2 = 0; kv2 < 2; kv2++)
      #pragma unroll
      for (int qt = 0; qt < 4; qt++)
        sacc[kv2][qt] = __builtin_amdgcn_mfma_f32_16x16x32_bf16(ak0[kv2], bq[qt][0], madd[kv2], 0, 0, 0);
    #pragma unroll
    for (int kv2 = 0; kv2 < 2; kv2++)
      #pragma unroll
      for (int qt = 0; qt < 4; qt++)
        sacc[kv2][qt] = __builtin_amdgcn_mfma_f32_16x16x32_bf16(ak1[kv2], bq[qt][1], sacc[kv2][qt], 0, 0, 0);
    __builtin_amdgcn_s_setprio(0);

    // P = exp2(S + maskterm) in-register; pack to 16x16x16 A-fragments via v_cvt_pk_bf16_f32
    bf16x4 pa[4][2];
    #pragma unroll
    for (int kv2 = 0; kv2 < 2; kv2++)
      #pragma unroll
      for (int qt = 0; qt < 4; qt++) {
        float p0 = exp2_fast(sacc[kv2][qt][0]);
        float p1 = exp2_fast(sacc[kv2][qt][1]);
        float p2 = exp2_fast(sacc[kv2][qt][2]);
        float p3 = exp2_fast(sacc[kv2][qt][3]);
        lsq[qt] += (p0 + p1) + (p2 + p3);
        union { uint32_t u[2]; bf16x4 v; } cv;
        asm("v_cvt_pk_bf16_f32 %0, %1, %2" : "=v"(cv.u[0]) : "v"(p0), "v"(p1));
        asm("v_cvt_pk_bf16_f32 %0, %1, %2" : "=v"(cv.u[1]) : "v"(p2), "v"(p3));
        pa[qt][kv2] = cv.v;
      }

    // O += P V over the slice: 16x16x16 MFMAs; B rows = d from VT half of LDS
    __builtin_amdgcn_s_setprio(1);
    #pragma unroll
    for (int kv2 = 0; kv2 < 2; kv2++) {
      bf16x4 vb[4];
      #pragma unroll
      for (int dt = 0; dt < 4; dt++)
        vb[dt] = *(const bf16x4*)&Vb[(dt * 16 + c16) * 72 + kv0 + kv2 * 16 + quad * 4];
      #pragma unroll
      for (int qt = 0; qt < 4; qt++)
        #pragma unroll
        for (int dt = 0; dt < 4; dt++)
          oacc[qt][dt] = __builtin_amdgcn_mfma_f32_16x16x16bf16_1k(pa[qt][kv2], vb[dt], oacc[qt][dt], 0, 0, 0);
    }
    __builtin_amdgcn_s_setprio(0);
    __syncthreads();      // (a) all reads of buf cb done -> reusable; (b) vmcnt(0) drains prefetch
  }

  // reduce per-lane partials across the 4 quads (value then depends on c16 only)
  #pragma unroll
  for (int qt = 0; qt < 4; qt++) {
    float v = lsq[qt];
    v += __shfl_xor(v, 16);
    v += __shfl_xor(v, 32);
    lsq[qt] = v;
  }

  // cross-wave kv-combine through the now-dead KV/Msall LDS
  float* Osc = (float*)&KV[0][0];               // 2 x 16KB (per wq) <= 36864B
  float* Lsc = Msall;                           // 2 x 64 floats
  if (wkv == 1) {
    float* Ob = Osc + wq * 4096;
    #pragma unroll
    for (int qt = 0; qt < 4; qt++)
      #pragma unroll
      for (int dt = 0; dt < 4; dt++)
        #pragma unroll
        for (int r = 0; r < 4; r++)
          Ob[(qt * 16 + quad * 4 + r) * 64 + dt * 16 + c16] = oacc[qt][dt][r];
    if (lane < 16)
      #pragma unroll
      for (int qt = 0; qt < 4; qt++) Lsc[wq * 64 + qt * 16 + lane] = lsq[qt];
  }
  __syncthreads();
  if (wkv == 0) {
    float* Ob = Osc + wq * 4096;
    u16* Obase = Om + (size_t)b * SH + (size_t)qb * 128 * HDIM + h * 64;
    #pragma unroll
    for (int qt = 0; qt < 4; qt++)
      #pragma unroll
      for (int r = 0; r < 4; r++) {
        float l = __shfl(lsq[qt], quad * 4 + r) + Lsc[wq * 64 + qt * 16 + quad * 4 + r];
        float rinv = 1.0f / l;
        int lr = qw0 + qt * 16 + quad * 4 + r;
        #pragma unroll
        for (int dt = 0; dt < 4; dt++) {
          float o = oacc[qt][dt][r] + Ob[(qt * 16 + quad * 4 + r) * 64 + dt * 16 + c16];
          Obase[(size_t)lr * HDIM + dt * 16 + c16] = f2bf(o * rinv);
        }
      }
  }
}

extern "C" void kernel_launch(void* const* d_in, const int* in_sizes, int n_in,
                              void* d_out, int out_size, void* d_ws, size_t ws_size,
                              hipStream_t stream)
{
  (void)in_sizes; (void)n_in; (void)out_size; (void)ws_size;
  const float* q_in = (const float*)d_in[0];
  const float* k_in = (const float*)d_in[1];
  const float* v_in = (const float*)d_in[2];
  const float* mask = (const float*)d_in[3];
  const float* wq   = (const float*)d_in[4];
  const float* bq   = (const float*)d_in[5];
  const float* wk   = (const float*)d_in[6];
  const float* bk   = (const float*)d_in[7];
  const float* wv   = (const float*)d_in[8];
  const float* bv   = (const float*)d_in[9];
  const float* wo   = (const float*)d_in[10];
  const float* bo   = (const float*)d_in[11];

  u16* ws  = (u16*)d_ws;                 // bf16 elems: 4x1M wt + 3x4M in + 5x4M acts = 72 MB
  u16* wqt = ws;
  u16* wkt = wqt + (1u << 20);
  u16* wvt = wkt + (1u << 20);
  u16* wot = wvt + (1u << 20);
  u16* qi_ = wot + (1u << 20);
  u16* ki_ = qi_ + (4u << 20);
  u16* vi_ = ki_ + (4u << 20);
  u16* qb_ = vi_ + (4u << 20);
  u16* kb_ = qb_ + (4u << 20);
  u16* vb_ = kb_ + (4u << 20);
  u16* vtb = vb_ + (4u << 20);
  u16* ob_ = vtb + (4u << 20);

  dim3 blk(256);
  k_cvt3<<<dim3(2048, 3), blk, 0, stream>>>(q_in, k_in, v_in, qi_, ki_, vi_);
  k_tr_w4<<<dim3(16, 16, 4), blk, 0, stream>>>(wq, wk, wv, wo, wqt, wkt, wvt, wot);
  k_gemm_qkv<<<dim3(32, 8, 3), blk, 0, stream>>>(qi_, ki_, vi_, wqt, wkt, wvt, bq, bk, bv, qb_, kb_, vb_);
  k_tr_v<<<dim3(32, 32), blk, 0, stream>>>(vb_, vtb);
  k_attn<<<dim3(16, 16, 2), blk, 0, stream>>>(qb_, kb_, vtb, mask, ob_);
  k_gemm_o<<<dim3(32, 16), blk, 0, stream>>>(ob_, wot, bo, (float*)d_out);
}